// Round 19
// baseline (130.244 us; speedup 1.0000x reference)
//
#include <hip/hip_runtime.h>
#include <hip/hip_bf16.h>
#include <cstdint>
#include <cstddef>

#define MSETS 4096
#define SET_SZ 1024
#define NBINS 128
#define DMODEL 1024
#define DPHI 512
#define WIN 48

typedef float f32x4 __attribute__((ext_vector_type(4)));
typedef __bf16 bf16x8 __attribute__((ext_vector_type(8)));
typedef unsigned short u16x8 __attribute__((ext_vector_type(8)));

__device__ inline float gelu_exact(float x) {
    return 0.5f * x * (1.0f + erff(x * 0.70710678118654752f));
}

__device__ inline void gload16(const char* g, char* l) {
    __builtin_amdgcn_global_load_lds(
        (const __attribute__((address_space(1))) unsigned int*)g,
        (__attribute__((address_space(3))) unsigned int*)l,
        16, 0, 0);
}

__device__ inline void cvt4(const float* __restrict__ s, __hip_bfloat16* __restrict__ d) {
    float4 v = *(const float4*)s;
    union { __hip_bfloat16 h[4]; ushort4 u; } cv;
    cv.h[0] = __float2bfloat16(v.x);
    cv.h[1] = __float2bfloat16(v.y);
    cv.h[2] = __float2bfloat16(v.z);
    cv.h[3] = __float2bfloat16(v.w);
    *(ushort4*)d = cv.u;
}

// ---------------------------------------------------- merged front bodies ---
// low-VGPR only (R8 lesson).

__device__ void prep_body(int b, int tid,
    const float* __restrict__ count_w, const float* __restrict__ f1_w,
    const float* __restrict__ f2_w, const float* __restrict__ rf_w,
    const float* __restrict__ rc_w,
    __hip_bfloat16* __restrict__ cwb, __hip_bfloat16* __restrict__ f1b,
    __hip_bfloat16* __restrict__ f2b, __hip_bfloat16* __restrict__ catB,
    __hip_bfloat16* __restrict__ rfBb, __hip_bfloat16* __restrict__ rc_wT) {
    int i = b * 256 + tid;
    if (i < 16384) {
        cvt4(count_w + (size_t)i * 4, cwb + (size_t)i * 4);
    } else if (i < 147456) {
        int j = i - 16384;
        cvt4(f1_w + (size_t)j * 4, f1b + (size_t)j * 4);
    } else if (i < 212992) {
        int j = i - 147456;
        cvt4(f2_w + (size_t)j * 4, f2b + (size_t)j * 4);
    } else if (i < 475136) {
        int j = i - 212992;
        int n = j >> 8, c = j & 255;
        cvt4(rf_w + (size_t)n * 2048 + c * 4, catB + (size_t)n * 1152 + c * 4);
    } else if (i < 737280) {
        int j = i - 475136;
        int n = j >> 8, c = j & 255;
        cvt4(rf_w + (size_t)n * 2048 + 1024 + c * 4, rfBb + (size_t)n * 1024 + c * 4);
    } else if (i < 770048) {
        int j = i - 737280;
        int bb = j >> 8, jc = (j & 255) * 4;
        union { __hip_bfloat16 h[4]; ushort4 u; } cv;
#pragma unroll
        for (int r = 0; r < 4; ++r)
            cv.h[r] = __float2bfloat16(rc_w[(size_t)(jc + r) * NBINS + bb]);
        *(ushort4*)(rc_wT + (size_t)bb * 1024 + jc) = cv.u;
    }
}

// per-wave sub-histograms: 4x128 bins -> ~4x less LDS-atomic serialization.
// NOTE: blockDim=256, array is 512 ints -> init needs TWO stores per thread
// (R18 bug: `if(tid<512) hist[tid]=0` left [256,512) uninitialized).
__device__ void counts_body(int m, int tid, float* smem,
    const int* __restrict__ token_ids, const int* __restrict__ set_indices,
    const int* __restrict__ set_sizes, const float* __restrict__ states,
    __hip_bfloat16* __restrict__ catA, __hip_bfloat16* __restrict__ fusedc) {
    int* hist = (int*)smem;                         // [4][128]
    const int wv = (tid >> 6) * NBINS;
    hist[tid] = 0;
    hist[tid + 256] = 0;
    __syncthreads();
    const int* row = set_indices + (size_t)m * SET_SZ;
#pragma unroll
    for (int q = 0; q < 4; ++q) {
        int idx = row[q * 256 + tid];
        if (idx >= 0) {
            int tok = token_ids[idx];
            atomicAdd(&hist[wv + (((tok & 127) * 39 + 13) & 127)], 1);
        }
    }
    cvt4(states + (size_t)m * DMODEL + tid * 4,
         catA + (size_t)m * 1152 + tid * 4);
    __syncthreads();
    if (tid < NBINS) {
        int cnt = hist[tid] + hist[NBINS + tid] + hist[2 * NBINS + tid]
                + hist[3 * NBINS + tid];
        float denom = fmaxf((float)set_sizes[m], 1.0f);
        __hip_bfloat16 c = __float2bfloat16((float)cnt / denom);
        catA[(size_t)m * 1152 + 1024 + tid] = c;
        fusedc[(size_t)m * 1024 + 512 + tid] = c;
    }
}

__device__ void geom_body(int i, int tid, float* smem,
    const float* __restrict__ pos, float* __restrict__ out2) {
    float* sp = smem;
    for (int j = tid; j < MSETS / 4; j += 256)
        ((float4*)sp)[j] = ((const float4*)pos)[j];
    __syncthreads();
    float pi = sp[i];
    float4* row = (float4*)(out2 + (size_t)i * MSETS);
    const float4* sp4 = (const float4*)sp;
    for (int j4 = tid; j4 < MSETS / 4; j4 += 256) {
        float4 p = sp4[j4];
        float4 v;
        v.x = -fabsf(pi - p.x);
        v.y = -fabsf(pi - p.y);
        v.z = -fabsf(pi - p.z);
        v.w = -fabsf(pi - p.w);
        row[j4] = v;
    }
}

__device__ void b2_body(int n, int tid, float* smem,
    const float* __restrict__ rf_w, const float* __restrict__ rf_b,
    const float* __restrict__ rc_b, float* __restrict__ b2) {
    float* red = smem;
    const float* row = rf_w + (size_t)n * (2 * DMODEL) + DMODEL;
    float a = 0.0f;
    for (int j = tid; j < DMODEL; j += 256) a = fmaf(rc_b[j], row[j], a);
    for (int o = 32; o > 0; o >>= 1) a += __shfl_down(a, o, 64);
    if ((tid & 63) == 0) red[tid >> 6] = a;
    __syncthreads();
    if (tid == 0) b2[n] = rf_b[n] + red[0] + red[1] + red[2] + red[3];
}

// [0,3008) prep | [3008,7104) counts | [7104,11200) geom_bias | [11200,12224) b2
__global__ __launch_bounds__(256) void front2_kernel(
    const float* __restrict__ count_w, const float* __restrict__ f1_w,
    const float* __restrict__ f2_w, const float* __restrict__ rf_w,
    const float* __restrict__ rc_w,
    __hip_bfloat16* __restrict__ cwb, __hip_bfloat16* __restrict__ f1b,
    __hip_bfloat16* __restrict__ f2b, __hip_bfloat16* __restrict__ catB,
    __hip_bfloat16* __restrict__ rfBb, __hip_bfloat16* __restrict__ rc_wT,
    const int* __restrict__ token_ids, const int* __restrict__ set_indices,
    const int* __restrict__ set_sizes, const float* __restrict__ states,
    __hip_bfloat16* __restrict__ catA, __hip_bfloat16* __restrict__ fusedc,
    const float* __restrict__ pos, float* __restrict__ out_gb,
    const float* __restrict__ rf_b, const float* __restrict__ rc_b,
    float* __restrict__ b2) {
    __shared__ float smem[4096];
    const int b = blockIdx.x;
    const int tid = threadIdx.x;
    if (b < 3008) {
        prep_body(b, tid, count_w, f1_w, f2_w, rf_w, rc_w,
                  cwb, f1b, f2b, catB, rfBb, rc_wT);
    } else if (b < 7104) {
        counts_body(b - 3008, tid, smem, token_ids, set_indices, set_sizes,
                    states, catA, fusedc);
    } else if (b < 11200) {
        geom_body(b - 7104, tid, smem, pos, out_gb);
    } else {
        b2_body(b - 11200, tid, smem, rf_w, rf_b, rc_b, b2);
    }
}

// ---------------------------------------------------- proj_geom (banded) ----
__device__ void projgeom_body(int bx, int by, int tid, char* smraw,
    const float* __restrict__ geom_w, const float* __restrict__ geom_b,
    __hip_bfloat16* __restrict__ fusedc) {
    float (*w)[608] = (float (*)[608])smraw;
    float* gbs = (float*)(smraw + 19456);
    const int p0 = bx * 8;
    const int i0 = by * 512;
    for (int t = tid; t < 8 * 608; t += 256) {
        int pr = t / 608, j = t - pr * 608;
        int src = i0 - WIN + j;
        w[pr][j] = (src >= 0 && src < MSETS)
                       ? geom_w[(size_t)(p0 + pr) * MSETS + src] : 0.0f;
    }
    if (tid < 8) gbs[tid] = geom_b[p0 + tid];
    __syncthreads();

    float r0[8], r1[8];
#pragma unroll
    for (int p = 0; p < 8; ++p) {
        const float* wr = &w[p][0];
        const int c0 = WIN + tid;
        const int c1 = WIN + 256 + tid;
        float a0[4] = {wr[c0], 0.0f, 0.0f, 0.0f};
        float a1[4] = {wr[c1], 0.0f, 0.0f, 0.0f};
        float f = 1.0f;
#pragma unroll
        for (int d = 1; d <= WIN; ++d) {
            f *= 0.36787944117144233f;
            a0[d & 3] = fmaf(f, wr[c0 - d] + wr[c0 + d], a0[d & 3]);
            a1[d & 3] = fmaf(f, wr[c1 - d] + wr[c1 + d], a1[d & 3]);
        }
        float gb = gbs[p];
        r0[p] = a0[0] + a0[1] + a0[2] + a0[3] + gb;
        r1[p] = a1[0] + a1[1] + a1[2] + a1[3] + gb;
    }
    union { __hip_bfloat16 h[8]; u16x8 v; } pk0, pk1;
#pragma unroll
    for (int p = 0; p < 8; ++p) {
        pk0.h[p] = __float2bfloat16(r0[p]);
        pk1.h[p] = __float2bfloat16(r1[p]);
    }
    *(u16x8*)(fusedc + (size_t)(i0 + tid) * 1024 + p0) = pk0.v;
    *(u16x8*)(fusedc + (size_t)(i0 + 256 + tid) * 1024 + p0) = pk1.v;
}

// ------------------------------------------------- bf16 MFMA GEMM body ------
// C[M,N] = A[M,K] @ B[N,K]^T + bias ; BM=128, BN template, BK=64, 4 waves 2x2.
template<int ACT, bool BF16OUT, int BN>
__device__ __forceinline__ void gemm_body(char* lds,
    const __hip_bfloat16* __restrict__ A, int lda,
    const __hip_bfloat16* __restrict__ B, int ldb,
    void* __restrict__ C, int ldc,
    const float* __restrict__ bias, int K, int bx, int by) {
    constexpr int BM = 128;
    constexpr int NF = BN / 32;
    constexpr int NBQ = BN * 8 / 256;
    char* As = lds;
    char* Bs = lds + BM * 128;

    const int tid = threadIdx.x;
    const int lane = tid & 63;
    const int wave = tid >> 6;
    const int wm = wave >> 1, wn = wave & 1;
    const int l16 = lane & 15, lq = lane >> 4;
    const int i0 = by * BM, j0 = bx * BN;

    const char* Ab = (const char*)A;
    const char* Bb = (const char*)B;
    size_t gA[4]; unsigned lA[4];
#pragma unroll
    for (int q = 0; q < 4; ++q) {
        int ws = q * 256 + wave * 64;
        int s = ws + lane;
        int r = s >> 3, pc = s & 7;
        int c = pc ^ (r & 7);
        gA[q] = (size_t)(i0 + r) * lda * 2 + c * 16;
        lA[q] = (unsigned)ws * 16u;
    }
    size_t gB[NBQ]; unsigned lB[NBQ];
#pragma unroll
    for (int q = 0; q < NBQ; ++q) {
        int ws = q * 256 + wave * 64;
        int s = ws + lane;
        int r = s >> 3, pc = s & 7;
        int c = pc ^ (r & 7);
        gB[q] = (size_t)(j0 + r) * ldb * 2 + c * 16;
        lB[q] = (unsigned)ws * 16u;
    }

    unsigned aoff[4][2], boff[NF][2];
#pragma unroll
    for (int kk = 0; kk < 2; ++kk) {
        int ca = kk * 4 + lq;
#pragma unroll
        for (int m = 0; m < 4; ++m) {
            int ra = wm * 64 + m * 16 + l16;
            aoff[m][kk] = (unsigned)(ra * 8 + (ca ^ (ra & 7))) * 16u;
        }
#pragma unroll
        for (int n = 0; n < NF; ++n) {
            int rb = wn * (BN / 2) + n * 16 + l16;
            boff[n][kk] = (unsigned)(rb * 8 + (ca ^ (rb & 7))) * 16u;
        }
    }

    f32x4 acc[4][NF] = {};
    const int nt = K >> 6;
    for (int t = 0; t < nt; ++t) {
        size_t go = (size_t)t * 128;
#pragma unroll
        for (int q = 0; q < 4; ++q) gload16(Ab + gA[q] + go, As + lA[q]);
#pragma unroll
        for (int q = 0; q < NBQ; ++q) gload16(Bb + gB[q] + go, Bs + lB[q]);
        __syncthreads();
#pragma unroll
        for (int kk = 0; kk < 2; ++kk) {
            bf16x8 af[4], bfv[NF];
#pragma unroll
            for (int m = 0; m < 4; ++m) af[m] = *(const bf16x8*)(As + aoff[m][kk]);
#pragma unroll
            for (int n = 0; n < NF; ++n) bfv[n] = *(const bf16x8*)(Bs + boff[n][kk]);
#pragma unroll
            for (int m = 0; m < 4; ++m)
#pragma unroll
                for (int n = 0; n < NF; ++n)
                    acc[m][n] = __builtin_amdgcn_mfma_f32_16x16x32_bf16(
                        af[m], bfv[n], acc[m][n], 0, 0, 0);
        }
        __syncthreads();
    }

    // C/D: col = lane&15, row = (lane>>4)*4 + reg  (m89-verified)
#pragma unroll
    for (int n = 0; n < NF; ++n) {
        int col = j0 + wn * (BN / 2) + n * 16 + l16;
        float bv = bias ? bias[col] : 0.0f;
#pragma unroll
        for (int m = 0; m < 4; ++m) {
            int row0 = i0 + wm * 64 + m * 16 + lq * 4;
#pragma unroll
            for (int j = 0; j < 4; ++j) {
                float v = acc[m][n][j] + bv;
                if (ACT == 1) v = gelu_exact(v);
                int row = row0 + j;
                if (BF16OUT)
                    ((__hip_bfloat16*)C)[(size_t)row * ldc + col] = __float2bfloat16(v);
                else
                    ((float*)C)[(size_t)row * ldc + col] = v;
            }
        }
    }
}

// 1-D grid + bijective XCD swizzle (grid % 8 == 0) + internal bx/by decode.
template<int ACT, bool BF16OUT, int BN>
__global__ __launch_bounds__(256) void gemm_mfma_swz(
    const __hip_bfloat16* __restrict__ A, int lda,
    const __hip_bfloat16* __restrict__ B, int ldb,
    void* __restrict__ C, int ldc,
    const float* __restrict__ bias, int K, int nbx) {
    __shared__ char lds[(128 + BN) * 128];
    const int cpx = gridDim.x >> 3;
    const int b = ((int)blockIdx.x & 7) * cpx + ((int)blockIdx.x >> 3);
    gemm_body<ACT, BF16OUT, BN>(lds, A, lda, B, ldb, C, ldc, bias, K,
                                b % nbx, b / nbx);
}

// -------------------- W2 split-K: 256 blocks, one BK=64 K-step each ----------
__global__ __launch_bounds__(256) void w2split_kernel(
    const __hip_bfloat16* __restrict__ rfBb,
    const __hip_bfloat16* __restrict__ rc_wT,
    __hip_bfloat16* __restrict__ w2part) {
    __shared__ char smraw[(128 + 64) * 128];
    const int b = blockIdx.x;
    const int kc = b >> 4, tile = b & 15;
    gemm_body<0, true, 64>(smraw, rfBb + kc * 64, DMODEL, rc_wT + kc * 64,
                           DMODEL, w2part + (size_t)kc * (DMODEL * NBINS),
                           NBINS, nullptr, 64, tile & 1, tile >> 1);
}

// ------------- merged: projgeom [0,512) | W2 reduce [512,576) ----------------
__global__ __launch_bounds__(256) void geomred_kernel(
    const float* __restrict__ geom_w, const float* __restrict__ geom_b,
    __hip_bfloat16* __restrict__ fusedc,
    const __hip_bfloat16* __restrict__ w2part,
    __hip_bfloat16* __restrict__ catB) {
    __shared__ char smraw[19488];
    const int b = blockIdx.x;
    if (b < 512) {
        projgeom_body(b & 63, b >> 6, threadIdx.x, smraw, geom_w, geom_b, fusedc);
    } else {
        int t = (b - 512) * 256 + threadIdx.x;    // 16384 threads x 8 elems
        int off = t * 8;
        float s[8] = {};
#pragma unroll
        for (int kc = 0; kc < 16; ++kc) {
            u16x8 v = *(const u16x8*)(w2part + (size_t)kc * (DMODEL * NBINS) + off);
#pragma unroll
            for (int e = 0; e < 8; ++e) {
                union { unsigned u; float f; } cv;
                cv.u = (unsigned)v[e] << 16;
                s[e] += cv.f;
            }
        }
        int row = off >> 7, col = off & 127;
        union { __hip_bfloat16 h[8]; u16x8 v; } pk;
#pragma unroll
        for (int e = 0; e < 8; ++e) pk.h[e] = __float2bfloat16(s[e]);
        *(u16x8*)(catB + (size_t)row * 1152 + 1024 + col) = pk.v;
    }
}

// ---------- merged: desc BN=128 [0,256) | projc BN=64 [256,512) --------------
// bijective XCD swizzle (512 % 8 == 0); desc A re-read 16x -> 8x vs BN=64
__global__ __launch_bounds__(256) void dualgemm_kernel(
    const __hip_bfloat16* __restrict__ catA,
    const __hip_bfloat16* __restrict__ catB,
    float* __restrict__ out_desc, const float* __restrict__ b2,
    const __hip_bfloat16* __restrict__ cwb,
    __hip_bfloat16* __restrict__ fusedc, const float* __restrict__ count_b) {
    __shared__ char smraw[(128 + 128) * 128];
    const int cpx = gridDim.x >> 3;   // 64
    const int b = ((int)blockIdx.x & 7) * cpx + ((int)blockIdx.x >> 3);
    if (b < 256) {
        gemm_body<0, false, 128>(smraw, catA, 1152, catB, 1152,
                                 out_desc, DMODEL, b2, 1152,
                                 b & 7, b >> 3);
    } else {
        int j = b - 256;
        gemm_body<0, true, 64>(smraw, catA + 1024, 1152, cwb, NBINS,
                               fusedc + DPHI, 2 * DPHI, count_b, NBINS,
                               j & 7, j >> 3);
    }
}

// ---------------------------------------------------------------- launch -----
extern "C" void kernel_launch(void* const* d_in, const int* in_sizes, int n_in,
                              void* d_out, int out_size, void* d_ws, size_t ws_size,
                              hipStream_t stream) {
    const int*   token_ids   = (const int*)d_in[0];
    const int*   set_indices = (const int*)d_in[1];
    const int*   set_sizes   = (const int*)d_in[2];
    const float* set_pos     = (const float*)d_in[3];
    const float* set_states  = (const float*)d_in[4];
    const float* geom_w      = (const float*)d_in[5];
    const float* geom_b      = (const float*)d_in[6];
    const float* count_w     = (const float*)d_in[7];
    const float* count_b     = (const float*)d_in[8];
    const float* rc_w        = (const float*)d_in[9];
    const float* rc_b        = (const float*)d_in[10];
    const float* rf_w        = (const float*)d_in[11];
    const float* rf_b        = (const float*)d_in[12];
    const float* f1_w        = (const float*)d_in[13];
    const float* f1_b        = (const float*)d_in[14];
    const float* f2_w        = (const float*)d_in[15];
    const float* f2_b        = (const float*)d_in[16];

    float* out_phi  = (float*)d_out;                       // [4096,512]
    float* out_desc = out_phi + (size_t)MSETS * DPHI;      // [4096,1024]
    float* out_gb   = out_desc + (size_t)MSETS * DMODEL;   // [4096,4096]

    char* w = (char*)d_ws;
    __hip_bfloat16* catA   = (__hip_bfloat16*)w;                 // [4096,1152]
    __hip_bfloat16* catB   = (__hip_bfloat16*)(w + 9437184);     // [1024,1152]
    __hip_bfloat16* fusedc = (__hip_bfloat16*)(w + 11796480);    // [4096,1024]
    __hip_bfloat16* hb     = (__hip_bfloat16*)(w + 20185088);    // [4096,512]
    __hip_bfloat16* w2part = hb;   // [16][1024][128] bf16 = 4MB, dead before L5
    __hip_bfloat16* cwb    = (__hip_bfloat16*)(w + 24379392);    // [512,128]
    __hip_bfloat16* f1b    = (__hip_bfloat16*)(w + 24510464);    // [512,1024]
    __hip_bfloat16* f2b    = (__hip_bfloat16*)(w + 25559040);    // [512,512]
    __hip_bfloat16* rfBb   = (__hip_bfloat16*)(w + 26083328);    // [1024,1024]
    __hip_bfloat16* rc_wT  = (__hip_bfloat16*)(w + 28180480);    // [128,1024]
    float*          b2     = (float*)(w + 28442624);             // [1024]

    // L1: merged low-VGPR front: prep + counts + geom_bias + b2
    front2_kernel<<<12224, 256, 0, stream>>>(
        count_w, f1_w, f2_w, rf_w, rc_w,
        cwb, f1b, f2b, catB, rfBb, rc_wT,
        token_ids, set_indices, set_sizes, set_states, catA, fusedc,
        set_pos, out_gb, rf_b, rc_b, b2);

    // L2: W2 split-K (256 blocks; 16 K-chunks x 16 tiles, 1 K-step each)
    w2split_kernel<<<256, 256, 0, stream>>>(rfBb, rc_wT, w2part);

    // L3: projgeom (512) || W2 reduce (64) -> catB[:, 1024:1152]
    geomred_kernel<<<576, 256, 0, stream>>>(geom_w, geom_b, fusedc,
                                            w2part, catB);

    // L4: desc_router BN=128 (256) || proj_counts (256) + XCD swizzle
    dualgemm_kernel<<<512, 256, 0, stream>>>(catA, catB, out_desc, b2,
                                             cwb, fusedc, count_b);

    // L5: h = gelu(fusedc @ f1_w^T + f1_b)   [256 blocks = 8 x 32, swizzled]
    gemm_mfma_swz<1, true, 64><<<256, 256, 0, stream>>>(
        fusedc, 2 * DPHI, f1b, 2 * DPHI, hb, DPHI, f1_b, 2 * DPHI, 8);

    // L6: phi_attn = h @ f2_w^T + f2_b   [256 blocks = 8 x 32, swizzled]
    gemm_mfma_swz<0, false, 64><<<256, 256, 0, stream>>>(
        hb, DPHI, f2b, DPHI, out_phi, DPHI, f2_b, DPHI, 8);
}

// Round 20
// 123.116 us; speedup vs baseline: 1.0579x; 1.0579x over previous
//
#include <hip/hip_runtime.h>
#include <hip/hip_bf16.h>
#include <cstdint>
#include <cstddef>

#define MSETS 4096
#define SET_SZ 1024
#define NBINS 128
#define DMODEL 1024
#define DPHI 512
#define WIN 48

typedef float f32x4 __attribute__((ext_vector_type(4)));
typedef __bf16 bf16x8 __attribute__((ext_vector_type(8)));
typedef unsigned short u16x8 __attribute__((ext_vector_type(8)));

__device__ inline float gelu_exact(float x) {
    return 0.5f * x * (1.0f + erff(x * 0.70710678118654752f));
}

__device__ inline void gload16(const char* g, char* l) {
    __builtin_amdgcn_global_load_lds(
        (const __attribute__((address_space(1))) unsigned int*)g,
        (__attribute__((address_space(3))) unsigned int*)l,
        16, 0, 0);
}

__device__ inline void cvt4(const float* __restrict__ s, __hip_bfloat16* __restrict__ d) {
    float4 v = *(const float4*)s;
    union { __hip_bfloat16 h[4]; ushort4 u; } cv;
    cv.h[0] = __float2bfloat16(v.x);
    cv.h[1] = __float2bfloat16(v.y);
    cv.h[2] = __float2bfloat16(v.z);
    cv.h[3] = __float2bfloat16(v.w);
    *(ushort4*)d = cv.u;
}

// ---------------------------------------------------- merged front bodies ---
// low-VGPR only (R8 lesson).

__device__ void prep_body(int b, int tid,
    const float* __restrict__ count_w, const float* __restrict__ f1_w,
    const float* __restrict__ f2_w, const float* __restrict__ rf_w,
    const float* __restrict__ rc_w,
    __hip_bfloat16* __restrict__ cwb, __hip_bfloat16* __restrict__ f1b,
    __hip_bfloat16* __restrict__ f2b, __hip_bfloat16* __restrict__ catB,
    __hip_bfloat16* __restrict__ rfBb, __hip_bfloat16* __restrict__ rc_wT) {
    int i = b * 256 + tid;
    if (i < 16384) {
        cvt4(count_w + (size_t)i * 4, cwb + (size_t)i * 4);
    } else if (i < 147456) {
        int j = i - 16384;
        cvt4(f1_w + (size_t)j * 4, f1b + (size_t)j * 4);
    } else if (i < 212992) {
        int j = i - 147456;
        cvt4(f2_w + (size_t)j * 4, f2b + (size_t)j * 4);
    } else if (i < 475136) {
        int j = i - 212992;
        int n = j >> 8, c = j & 255;
        cvt4(rf_w + (size_t)n * 2048 + c * 4, catB + (size_t)n * 1152 + c * 4);
    } else if (i < 737280) {
        int j = i - 475136;
        int n = j >> 8, c = j & 255;
        cvt4(rf_w + (size_t)n * 2048 + 1024 + c * 4, rfBb + (size_t)n * 1024 + c * 4);
    } else if (i < 770048) {
        int j = i - 737280;
        int bb = j >> 8, jc = (j & 255) * 4;
        union { __hip_bfloat16 h[4]; ushort4 u; } cv;
#pragma unroll
        for (int r = 0; r < 4; ++r)
            cv.h[r] = __float2bfloat16(rc_w[(size_t)(jc + r) * NBINS + bb]);
        *(ushort4*)(rc_wT + (size_t)bb * 1024 + jc) = cv.u;
    }
}

// per-wave sub-histograms [4][128]; blockDim=256 -> init = TWO stores/thread
__device__ void counts_body(int m, int tid, float* smem,
    const int* __restrict__ token_ids, const int* __restrict__ set_indices,
    const int* __restrict__ set_sizes, const float* __restrict__ states,
    __hip_bfloat16* __restrict__ catA, __hip_bfloat16* __restrict__ fusedc) {
    int* hist = (int*)smem;
    const int wv = (tid >> 6) * NBINS;
    hist[tid] = 0;
    hist[tid + 256] = 0;
    __syncthreads();
    const int* row = set_indices + (size_t)m * SET_SZ;
#pragma unroll
    for (int q = 0; q < 4; ++q) {
        int idx = row[q * 256 + tid];
        if (idx >= 0) {
            int tok = token_ids[idx];
            atomicAdd(&hist[wv + (((tok & 127) * 39 + 13) & 127)], 1);
        }
    }
    cvt4(states + (size_t)m * DMODEL + tid * 4,
         catA + (size_t)m * 1152 + tid * 4);
    __syncthreads();
    if (tid < NBINS) {
        int cnt = hist[tid] + hist[NBINS + tid] + hist[2 * NBINS + tid]
                + hist[3 * NBINS + tid];
        float denom = fmaxf((float)set_sizes[m], 1.0f);
        __hip_bfloat16 c = __float2bfloat16((float)cnt / denom);
        catA[(size_t)m * 1152 + 1024 + tid] = c;
        fusedc[(size_t)m * 1024 + 512 + tid] = c;
    }
}

__device__ void geom_body(int i, int tid, float* smem,
    const float* __restrict__ pos, float* __restrict__ out2) {
    float* sp = smem;
    for (int j = tid; j < MSETS / 4; j += 256)
        ((float4*)sp)[j] = ((const float4*)pos)[j];
    __syncthreads();
    float pi = sp[i];
    float4* row = (float4*)(out2 + (size_t)i * MSETS);
    const float4* sp4 = (const float4*)sp;
    for (int j4 = tid; j4 < MSETS / 4; j4 += 256) {
        float4 p = sp4[j4];
        float4 v;
        v.x = -fabsf(pi - p.x);
        v.y = -fabsf(pi - p.y);
        v.z = -fabsf(pi - p.z);
        v.w = -fabsf(pi - p.w);
        row[j4] = v;
    }
}

__device__ void b2_body(int n, int tid, float* smem,
    const float* __restrict__ rf_w, const float* __restrict__ rf_b,
    const float* __restrict__ rc_b, float* __restrict__ b2) {
    float* red = smem;
    const float* row = rf_w + (size_t)n * (2 * DMODEL) + DMODEL;
    float a = 0.0f;
    for (int j = tid; j < DMODEL; j += 256) a = fmaf(rc_b[j], row[j], a);
    for (int o = 32; o > 0; o >>= 1) a += __shfl_down(a, o, 64);
    if ((tid & 63) == 0) red[tid >> 6] = a;
    __syncthreads();
    if (tid == 0) b2[n] = rf_b[n] + red[0] + red[1] + red[2] + red[3];
}

// [0,3008) prep | [3008,7104) counts | [7104,11200) geom_bias | [11200,12224) b2
__global__ __launch_bounds__(256) void front2_kernel(
    const float* __restrict__ count_w, const float* __restrict__ f1_w,
    const float* __restrict__ f2_w, const float* __restrict__ rf_w,
    const float* __restrict__ rc_w,
    __hip_bfloat16* __restrict__ cwb, __hip_bfloat16* __restrict__ f1b,
    __hip_bfloat16* __restrict__ f2b, __hip_bfloat16* __restrict__ catB,
    __hip_bfloat16* __restrict__ rfBb, __hip_bfloat16* __restrict__ rc_wT,
    const int* __restrict__ token_ids, const int* __restrict__ set_indices,
    const int* __restrict__ set_sizes, const float* __restrict__ states,
    __hip_bfloat16* __restrict__ catA, __hip_bfloat16* __restrict__ fusedc,
    const float* __restrict__ pos, float* __restrict__ out_gb,
    const float* __restrict__ rf_b, const float* __restrict__ rc_b,
    float* __restrict__ b2) {
    __shared__ float smem[4096];
    const int b = blockIdx.x;
    const int tid = threadIdx.x;
    if (b < 3008) {
        prep_body(b, tid, count_w, f1_w, f2_w, rf_w, rc_w,
                  cwb, f1b, f2b, catB, rfBb, rc_wT);
    } else if (b < 7104) {
        counts_body(b - 3008, tid, smem, token_ids, set_indices, set_sizes,
                    states, catA, fusedc);
    } else if (b < 11200) {
        geom_body(b - 7104, tid, smem, pos, out_gb);
    } else {
        b2_body(b - 11200, tid, smem, rf_w, rf_b, rc_b, b2);
    }
}

// ---------------------------------------------------- proj_geom (banded) ----
__device__ void projgeom_body(int bx, int by, int tid, char* smraw,
    const float* __restrict__ geom_w, const float* __restrict__ geom_b,
    __hip_bfloat16* __restrict__ fusedc) {
    float (*w)[608] = (float (*)[608])smraw;
    float* gbs = (float*)(smraw + 19456);
    const int p0 = bx * 8;
    const int i0 = by * 512;
    for (int t = tid; t < 8 * 608; t += 256) {
        int pr = t / 608, j = t - pr * 608;
        int src = i0 - WIN + j;
        w[pr][j] = (src >= 0 && src < MSETS)
                       ? geom_w[(size_t)(p0 + pr) * MSETS + src] : 0.0f;
    }
    if (tid < 8) gbs[tid] = geom_b[p0 + tid];
    __syncthreads();

    float r0[8], r1[8];
#pragma unroll
    for (int p = 0; p < 8; ++p) {
        const float* wr = &w[p][0];
        const int c0 = WIN + tid;
        const int c1 = WIN + 256 + tid;
        float a0[4] = {wr[c0], 0.0f, 0.0f, 0.0f};
        float a1[4] = {wr[c1], 0.0f, 0.0f, 0.0f};
        float f = 1.0f;
#pragma unroll
        for (int d = 1; d <= WIN; ++d) {
            f *= 0.36787944117144233f;
            a0[d & 3] = fmaf(f, wr[c0 - d] + wr[c0 + d], a0[d & 3]);
            a1[d & 3] = fmaf(f, wr[c1 - d] + wr[c1 + d], a1[d & 3]);
        }
        float gb = gbs[p];
        r0[p] = a0[0] + a0[1] + a0[2] + a0[3] + gb;
        r1[p] = a1[0] + a1[1] + a1[2] + a1[3] + gb;
    }
    union { __hip_bfloat16 h[8]; u16x8 v; } pk0, pk1;
#pragma unroll
    for (int p = 0; p < 8; ++p) {
        pk0.h[p] = __float2bfloat16(r0[p]);
        pk1.h[p] = __float2bfloat16(r1[p]);
    }
    *(u16x8*)(fusedc + (size_t)(i0 + tid) * 1024 + p0) = pk0.v;
    *(u16x8*)(fusedc + (size_t)(i0 + 256 + tid) * 1024 + p0) = pk1.v;
}

// ------------------------------------------------- bf16 MFMA GEMM body ------
// C[M,N] = A[M,K] @ B[N,K]^T + bias ; BM=128, BN template, BK=64, 4 waves 2x2.
template<int ACT, bool BF16OUT, int BN>
__device__ __forceinline__ void gemm_body(char* lds,
    const __hip_bfloat16* __restrict__ A, int lda,
    const __hip_bfloat16* __restrict__ B, int ldb,
    void* __restrict__ C, int ldc,
    const float* __restrict__ bias, int K, int bx, int by) {
    constexpr int BM = 128;
    constexpr int NF = BN / 32;
    constexpr int NBQ = BN * 8 / 256;
    char* As = lds;
    char* Bs = lds + BM * 128;

    const int tid = threadIdx.x;
    const int lane = tid & 63;
    const int wave = tid >> 6;
    const int wm = wave >> 1, wn = wave & 1;
    const int l16 = lane & 15, lq = lane >> 4;
    const int i0 = by * BM, j0 = bx * BN;

    const char* Ab = (const char*)A;
    const char* Bb = (const char*)B;
    size_t gA[4]; unsigned lA[4];
#pragma unroll
    for (int q = 0; q < 4; ++q) {
        int ws = q * 256 + wave * 64;
        int s = ws + lane;
        int r = s >> 3, pc = s & 7;
        int c = pc ^ (r & 7);
        gA[q] = (size_t)(i0 + r) * lda * 2 + c * 16;
        lA[q] = (unsigned)ws * 16u;
    }
    size_t gB[NBQ]; unsigned lB[NBQ];
#pragma unroll
    for (int q = 0; q < NBQ; ++q) {
        int ws = q * 256 + wave * 64;
        int s = ws + lane;
        int r = s >> 3, pc = s & 7;
        int c = pc ^ (r & 7);
        gB[q] = (size_t)(j0 + r) * ldb * 2 + c * 16;
        lB[q] = (unsigned)ws * 16u;
    }

    unsigned aoff[4][2], boff[NF][2];
#pragma unroll
    for (int kk = 0; kk < 2; ++kk) {
        int ca = kk * 4 + lq;
#pragma unroll
        for (int m = 0; m < 4; ++m) {
            int ra = wm * 64 + m * 16 + l16;
            aoff[m][kk] = (unsigned)(ra * 8 + (ca ^ (ra & 7))) * 16u;
        }
#pragma unroll
        for (int n = 0; n < NF; ++n) {
            int rb = wn * (BN / 2) + n * 16 + l16;
            boff[n][kk] = (unsigned)(rb * 8 + (ca ^ (rb & 7))) * 16u;
        }
    }

    f32x4 acc[4][NF] = {};
    const int nt = K >> 6;
    for (int t = 0; t < nt; ++t) {
        size_t go = (size_t)t * 128;
#pragma unroll
        for (int q = 0; q < 4; ++q) gload16(Ab + gA[q] + go, As + lA[q]);
#pragma unroll
        for (int q = 0; q < NBQ; ++q) gload16(Bb + gB[q] + go, Bs + lB[q]);
        __syncthreads();
#pragma unroll
        for (int kk = 0; kk < 2; ++kk) {
            bf16x8 af[4], bfv[NF];
#pragma unroll
            for (int m = 0; m < 4; ++m) af[m] = *(const bf16x8*)(As + aoff[m][kk]);
#pragma unroll
            for (int n = 0; n < NF; ++n) bfv[n] = *(const bf16x8*)(Bs + boff[n][kk]);
#pragma unroll
            for (int m = 0; m < 4; ++m)
#pragma unroll
                for (int n = 0; n < NF; ++n)
                    acc[m][n] = __builtin_amdgcn_mfma_f32_16x16x32_bf16(
                        af[m], bfv[n], acc[m][n], 0, 0, 0);
        }
        __syncthreads();
    }

    // C/D: col = lane&15, row = (lane>>4)*4 + reg  (m89-verified)
#pragma unroll
    for (int n = 0; n < NF; ++n) {
        int col = j0 + wn * (BN / 2) + n * 16 + l16;
        float bv = bias ? bias[col] : 0.0f;
#pragma unroll
        for (int m = 0; m < 4; ++m) {
            int row0 = i0 + wm * 64 + m * 16 + lq * 4;
#pragma unroll
            for (int j = 0; j < 4; ++j) {
                float v = acc[m][n][j] + bv;
                if (ACT == 1) v = gelu_exact(v);
                int row = row0 + j;
                if (BF16OUT)
                    ((__hip_bfloat16*)C)[(size_t)row * ldc + col] = __float2bfloat16(v);
                else
                    ((float*)C)[(size_t)row * ldc + col] = v;
            }
        }
    }
}

// 1-D grid + bijective XCD swizzle (grid % 8 == 0) + internal bx/by decode.
template<int ACT, bool BF16OUT, int BN>
__global__ __launch_bounds__(256) void gemm_mfma_swz(
    const __hip_bfloat16* __restrict__ A, int lda,
    const __hip_bfloat16* __restrict__ B, int ldb,
    void* __restrict__ C, int ldc,
    const float* __restrict__ bias, int K, int nbx) {
    __shared__ char lds[(128 + BN) * 128];
    const int cpx = gridDim.x >> 3;
    const int b = ((int)blockIdx.x & 7) * cpx + ((int)blockIdx.x >> 3);
    gemm_body<ACT, BF16OUT, BN>(lds, A, lda, B, ldb, C, ldc, bias, K,
                                b % nbx, b / nbx);
}

// -------------------- W2 split-K: 256 blocks, one BK=64 K-step each ----------
__global__ __launch_bounds__(256) void w2split_kernel(
    const __hip_bfloat16* __restrict__ rfBb,
    const __hip_bfloat16* __restrict__ rc_wT,
    __hip_bfloat16* __restrict__ w2part) {
    __shared__ char smraw[(128 + 64) * 128];
    const int b = blockIdx.x;
    const int kc = b >> 4, tile = b & 15;
    gemm_body<0, true, 64>(smraw, rfBb + kc * 64, DMODEL, rc_wT + kc * 64,
                           DMODEL, w2part + (size_t)kc * (DMODEL * NBINS),
                           NBINS, nullptr, 64, tile & 1, tile >> 1);
}

// ------------- merged: projgeom [0,512) | W2 reduce [512,576) ----------------
__global__ __launch_bounds__(256) void geomred_kernel(
    const float* __restrict__ geom_w, const float* __restrict__ geom_b,
    __hip_bfloat16* __restrict__ fusedc,
    const __hip_bfloat16* __restrict__ w2part,
    __hip_bfloat16* __restrict__ catB) {
    __shared__ char smraw[19488];
    const int b = blockIdx.x;
    if (b < 512) {
        projgeom_body(b & 63, b >> 6, threadIdx.x, smraw, geom_w, geom_b, fusedc);
    } else {
        int t = (b - 512) * 256 + threadIdx.x;    // 16384 threads x 8 elems
        int off = t * 8;
        float s[8] = {};
#pragma unroll
        for (int kc = 0; kc < 16; ++kc) {
            u16x8 v = *(const u16x8*)(w2part + (size_t)kc * (DMODEL * NBINS) + off);
#pragma unroll
            for (int e = 0; e < 8; ++e) {
                union { unsigned u; float f; } cv;
                cv.u = (unsigned)v[e] << 16;
                s[e] += cv.f;
            }
        }
        int row = off >> 7, col = off & 127;
        union { __hip_bfloat16 h[8]; u16x8 v; } pk;
#pragma unroll
        for (int e = 0; e < 8; ++e) pk.h[e] = __float2bfloat16(s[e]);
        *(u16x8*)(catB + (size_t)row * 1152 + 1024 + col) = pk.v;
    }
}

// ---------------- merged launch: desc [0,512) | projc [512,768) --------------
// BN=64 both (R19 lesson: BN=128 in merged kernel = LDS/VGPR max-over-bodies)
__global__ __launch_bounds__(256) void dualgemm_kernel(
    const __hip_bfloat16* __restrict__ catA,
    const __hip_bfloat16* __restrict__ catB,
    float* __restrict__ out_desc, const float* __restrict__ b2,
    const __hip_bfloat16* __restrict__ cwb,
    __hip_bfloat16* __restrict__ fusedc, const float* __restrict__ count_b) {
    __shared__ char smraw[(128 + 64) * 128];
    const int cpx = gridDim.x >> 3;   // 96
    const int b = ((int)blockIdx.x & 7) * cpx + ((int)blockIdx.x >> 3);
    if (b < 512) {
        gemm_body<0, false, 64>(smraw, catA, 1152, catB, 1152,
                                out_desc, DMODEL, b2, 1152,
                                b & 15, b >> 4);
    } else {
        int j = b - 512;
        gemm_body<0, true, 64>(smraw, catA + 1024, 1152, cwb, NBINS,
                               fusedc + DPHI, 2 * DPHI, count_b, NBINS,
                               j & 7, j >> 3);
    }
}

// ---------------------------------------------------------------- launch -----
extern "C" void kernel_launch(void* const* d_in, const int* in_sizes, int n_in,
                              void* d_out, int out_size, void* d_ws, size_t ws_size,
                              hipStream_t stream) {
    const int*   token_ids   = (const int*)d_in[0];
    const int*   set_indices = (const int*)d_in[1];
    const int*   set_sizes   = (const int*)d_in[2];
    const float* set_pos     = (const float*)d_in[3];
    const float* set_states  = (const float*)d_in[4];
    const float* geom_w      = (const float*)d_in[5];
    const float* geom_b      = (const float*)d_in[6];
    const float* count_w     = (const float*)d_in[7];
    const float* count_b     = (const float*)d_in[8];
    const float* rc_w        = (const float*)d_in[9];
    const float* rc_b        = (const float*)d_in[10];
    const float* rf_w        = (const float*)d_in[11];
    const float* rf_b        = (const float*)d_in[12];
    const float* f1_w        = (const float*)d_in[13];
    const float* f1_b        = (const float*)d_in[14];
    const float* f2_w        = (const float*)d_in[15];
    const float* f2_b        = (const float*)d_in[16];

    float* out_phi  = (float*)d_out;                       // [4096,512]
    float* out_desc = out_phi + (size_t)MSETS * DPHI;      // [4096,1024]
    float* out_gb   = out_desc + (size_t)MSETS * DMODEL;   // [4096,4096]

    char* w = (char*)d_ws;
    __hip_bfloat16* catA   = (__hip_bfloat16*)w;                 // [4096,1152]
    __hip_bfloat16* catB   = (__hip_bfloat16*)(w + 9437184);     // [1024,1152]
    __hip_bfloat16* fusedc = (__hip_bfloat16*)(w + 11796480);    // [4096,1024]
    __hip_bfloat16* hb     = (__hip_bfloat16*)(w + 20185088);    // [4096,512]
    __hip_bfloat16* w2part = hb;   // [16][1024][128] bf16 = 4MB, dead before L5
    __hip_bfloat16* cwb    = (__hip_bfloat16*)(w + 24379392);    // [512,128]
    __hip_bfloat16* f1b    = (__hip_bfloat16*)(w + 24510464);    // [512,1024]
    __hip_bfloat16* f2b    = (__hip_bfloat16*)(w + 25559040);    // [512,512]
    __hip_bfloat16* rfBb   = (__hip_bfloat16*)(w + 26083328);    // [1024,1024]
    __hip_bfloat16* rc_wT  = (__hip_bfloat16*)(w + 28180480);    // [128,1024]
    float*          b2     = (float*)(w + 28442624);             // [1024]

    // L1: merged low-VGPR front: prep + counts + geom_bias + b2
    front2_kernel<<<12224, 256, 0, stream>>>(
        count_w, f1_w, f2_w, rf_w, rc_w,
        cwb, f1b, f2b, catB, rfBb, rc_wT,
        token_ids, set_indices, set_sizes, set_states, catA, fusedc,
        set_pos, out_gb, rf_b, rc_b, b2);

    // L2: W2 split-K (256 blocks; 16 K-chunks x 16 tiles, 1 K-step each)
    w2split_kernel<<<256, 256, 0, stream>>>(rfBb, rc_wT, w2part);

    // L3: projgeom (512) || W2 reduce (64) -> catB[:, 1024:1152]
    geomred_kernel<<<576, 256, 0, stream>>>(geom_w, geom_b, fusedc,
                                            w2part, catB);

    // L4: desc_router (K=1152, 512 blocks) || proj_counts (256) + XCD swizzle
    dualgemm_kernel<<<768, 256, 0, stream>>>(catA, catB, out_desc, b2,
                                             cwb, fusedc, count_b);

    // L5: h = gelu(fusedc @ f1_w^T + f1_b)   [256 blocks = 8 x 32, swizzled]
    gemm_mfma_swz<1, true, 64><<<256, 256, 0, stream>>>(
        fusedc, 2 * DPHI, f1b, 2 * DPHI, hb, DPHI, f1_b, 2 * DPHI, 8);

    // L6: phi_attn = h @ f2_w^T + f2_b   [256 blocks = 8 x 32, swizzled]
    gemm_mfma_swz<0, false, 64><<<256, 256, 0, stream>>>(
        hb, DPHI, f2b, DPHI, out_phi, DPHI, f2_b, DPHI, 8);
}